// Round 1
// baseline (1775.993 us; speedup 1.0000x reference)
//
#include <hip/hip_runtime.h>
#include <hip/hip_bf16.h>
#include <math.h>

#define T_TOK 2048
#define HID   2048
#define NE    32
#define DF    1024
#define DSZ   4096
#define TOPK  6
#define NGRP  8
#define TOPKG 4
#define RSCALE 2.5f

typedef __attribute__((ext_vector_type(8))) short short8;
typedef __attribute__((ext_vector_type(4))) float f32x4;

static __device__ __forceinline__ unsigned short f2b(float f) {
    union { float f; unsigned u; } v; v.f = f;
    unsigned r = v.u + 0x7fffu + ((v.u >> 16) & 1u);
    return (unsigned short)(r >> 16);
}

// ---------------- router ----------------
__global__ void router_kernel(const float* __restrict__ x,
                              const float* __restrict__ rw,
                              const float* __restrict__ rb,
                              int* __restrict__ tidx, float* __restrict__ tw,
                              int* __restrict__ counts) {
    __shared__ float xs[HID];
    __shared__ float part[256];
    __shared__ float scores[NE];
    __shared__ float sfc[NE];
    int t = blockIdx.x;
    int tid = threadIdx.x;
    for (int i = tid; i < HID / 4; i += 256) {
        ((float4*)xs)[i] = ((const float4*)(x + (size_t)t * HID))[i];
    }
    __syncthreads();
    int e = tid & 31, ch = tid >> 5;
    const float* w = rw + (size_t)e * HID + ch * 256;
    const float* xv = xs + ch * 256;
    float p = 0.f;
    #pragma unroll 8
    for (int k = 0; k < 256; ++k) p += xv[k] * w[k];
    part[tid] = p;
    __syncthreads();
    if (tid < 32) {
        float l = 0.f;
        #pragma unroll
        for (int c = 0; c < 8; ++c) l += part[c * 32 + tid];
        float s = 1.f / (1.f + expf(-l));
        scores[tid] = s;
        sfc[tid] = s + rb[tid];
    }
    __syncthreads();
    if (tid == 0) {
        float gs[NGRP];
        for (int g = 0; g < NGRP; ++g) {
            float v[4];
            for (int i = 0; i < 4; ++i) v[i] = sfc[g * 4 + i];
            int bi = 0;
            for (int i = 1; i < 4; ++i) if (v[i] > v[bi]) bi = i;
            float m1 = v[bi]; v[bi] = -INFINITY;
            int bj = 0;
            for (int i = 1; i < 4; ++i) if (v[i] > v[bj]) bj = i;
            gs[g] = m1 + v[bj];
        }
        bool gsel[NGRP];
        for (int g = 0; g < NGRP; ++g) gsel[g] = false;
        for (int k = 0; k < TOPKG; ++k) {
            int bi = -1; float b = -INFINITY;
            for (int g = 0; g < NGRP; ++g)
                if (!gsel[g] && gs[g] > b) { b = gs[g]; bi = g; }
            gsel[bi] = true;
        }
        float masked[NE];
        for (int i = 0; i < NE; ++i) masked[i] = gsel[i >> 2] ? sfc[i] : 0.0f;
        int sel[TOPK]; float wv[TOPK]; float wsum = 0.f;
        for (int k = 0; k < TOPK; ++k) {
            int bi = -1; float b = -INFINITY;
            for (int i = 0; i < NE; ++i)
                if (masked[i] > b) { b = masked[i]; bi = i; }
            masked[bi] = -INFINITY;
            sel[k] = bi; wv[k] = scores[bi]; wsum += wv[k];
        }
        float inv = RSCALE / (wsum + 1e-20f);
        for (int k = 0; k < TOPK; ++k) {
            tidx[t * TOPK + k] = sel[k];
            tw[t * TOPK + k] = wv[k] * inv;
            atomicAdd(&counts[sel[k]], 1);
        }
    }
}

__global__ void scan_kernel(const int* __restrict__ counts, int* __restrict__ offsets) {
    if (threadIdx.x == 0) {
        int a = 0;
        for (int e2 = 0; e2 < NE; ++e2) { offsets[e2] = a; a += counts[e2]; }
        offsets[NE] = a;
    }
}

__global__ void scatter_kernel(const int* __restrict__ tidx, const float* __restrict__ tw,
                               const int* __restrict__ offsets, int* __restrict__ cursors,
                               int* __restrict__ perm, float* __restrict__ pw) {
    int t = blockIdx.x * blockDim.x + threadIdx.x;
    if (t >= T_TOK) return;
    for (int k = 0; k < TOPK; ++k) {
        int e = tidx[t * TOPK + k];
        int pos = atomicAdd(&cursors[e], 1);
        int slot = offsets[e] + pos;
        perm[slot] = t;
        pw[slot] = tw[t * TOPK + k];
    }
}

// ---------------- GEMM ----------------
// MODE 0: shared up   : A=x fp32 [2048,2048], B=shared_up [2048,4096], C=shact bf16, relu2
// MODE 1: shared down : A=shact bf16 [2048,4096], B=shared_down [4096,2048], C=out fp32 store
// MODE 2: routed up   : A=x fp32 gathered(perm), B=w_up[e] [2048,1024], C=act bf16, relu2*pw
// MODE 3: routed down : A=act bf16 (slots), B=w_down[e] [1024,2048], C=out fp32 atomicAdd
template<int MODE>
__global__ __launch_bounds__(256, 2)
void gemm_kernel(const void* __restrict__ Ain, const float* __restrict__ Bin,
                 void* __restrict__ Cout, const int* __restrict__ offsets,
                 const int* __restrict__ perm, const float* __restrict__ pw,
                 float* __restrict__ outbuf) {
    constexpr int K = (MODE == 0 || MODE == 2) ? HID : (MODE == 1 ? DSZ : DF);
    constexpr int N = (MODE == 0) ? DSZ : (MODE == 2 ? DF : HID);
    constexpr int LDA = (MODE == 0 || MODE == 2) ? HID : (MODE == 1 ? DSZ : DF);
    constexpr bool ABF = (MODE == 1 || MODE == 3);
    constexpr bool GATH = (MODE == 2);

    __shared__ __align__(16) char lds[32768];
    char* As = lds;
    char* Bs = lds + 16384;

    int tid = threadIdx.x;
    int lane = tid & 63, wvid = tid >> 6, wr = wvid >> 1, wc = wvid & 1;

    int row0, rowEnd;
    const float* B = Bin;
    if (MODE == 2 || MODE == 3) {
        int e = blockIdx.z;
        int off = offsets[e], end = offsets[e + 1];
        row0 = off + blockIdx.y * 128;
        if (row0 >= end) return;
        rowEnd = end;
        B = Bin + (size_t)e * K * N;
    } else {
        row0 = blockIdx.y * 128;
        rowEnd = 1 << 30;
    }
    int n0 = blockIdx.x * 128;

    // A staging role: 4 passes, row = p*32 + (tid>>3), k chunk = (tid&7)*8
    int sr = tid >> 3;
    int sc = tid & 7;
    size_t asrc[4];
    #pragma unroll
    for (int p = 0; p < 4; ++p) {
        int gr = row0 + p * 32 + sr;
        if ((MODE == 2 || MODE == 3) && gr > rowEnd - 1) gr = rowEnd - 1;
        int s = GATH ? perm[gr] : gr;
        asrc[p] = (size_t)s * LDA;
    }
    // B staging role: col = tid&127, khalf = tid>>7
    int bcol = tid & 127;
    int bkh = tid >> 7;

    f32x4 acc[4][4] = {};

    for (int k0 = 0; k0 < K; k0 += 64) {
        __syncthreads();
        // stage A: 128 rows x 64 k, fp32->bf16 (or bf16 direct), XOR swizzle
        #pragma unroll
        for (int p = 0; p < 4; ++p) {
            int r = p * 32 + sr;
            short8 av;
            if (!ABF) {
                const float* src = (const float*)Ain + asrc[p] + k0 + sc * 8;
                float4 v0 = *(const float4*)(src);
                float4 v1 = *(const float4*)(src + 4);
                av[0] = (short)f2b(v0.x); av[1] = (short)f2b(v0.y);
                av[2] = (short)f2b(v0.z); av[3] = (short)f2b(v0.w);
                av[4] = (short)f2b(v1.x); av[5] = (short)f2b(v1.y);
                av[6] = (short)f2b(v1.z); av[7] = (short)f2b(v1.w);
            } else {
                const unsigned short* src = (const unsigned short*)Ain + asrc[p] + k0 + sc * 8;
                av = *(const short8*)(src);
            }
            *(short8*)(As + r * 128 + ((sc * 16) ^ ((r & 7) << 4))) = av;
        }
        // stage B transposed: Bs[col][k], read along K (coalesced across lanes)
        {
            const float* bs = B + (size_t)(k0 + bkh * 32) * N + (n0 + bcol);
            short8 bv[4];
            #pragma unroll
            for (int q = 0; q < 4; ++q)
                #pragma unroll
                for (int i = 0; i < 8; ++i)
                    bv[q][i] = (short)f2b(bs[(size_t)(q * 8 + i) * N]);
            int swz = (bcol & 7) << 4;
            #pragma unroll
            for (int q = 0; q < 4; ++q)
                *(short8*)(Bs + bcol * 128 + ((bkh * 64 + q * 16) ^ swz)) = bv[q];
        }
        __syncthreads();
        // compute: 2 k-steps of 32
        #pragma unroll
        for (int ks = 0; ks < 2; ++ks) {
            int kg = lane >> 4, r16 = lane & 15;
            short8 af[4], bfr[4];
            #pragma unroll
            for (int m = 0; m < 4; ++m) {
                int r = wr * 64 + m * 16 + r16;
                af[m] = *(const short8*)(As + r * 128 + ((ks * 64 + kg * 16) ^ ((r & 7) << 4)));
            }
            #pragma unroll
            for (int n = 0; n < 4; ++n) {
                int c = wc * 64 + n * 16 + r16;
                bfr[n] = *(const short8*)(Bs + c * 128 + ((ks * 64 + kg * 16) ^ ((c & 7) << 4)));
            }
            #pragma unroll
            for (int m = 0; m < 4; ++m)
                #pragma unroll
                for (int n = 0; n < 4; ++n)
                    acc[m][n] = __builtin_amdgcn_mfma_f32_16x16x32_bf16(af[m], bfr[n], acc[m][n], 0, 0, 0);
        }
    }

    // epilogue. D frag: col = lane&15, row = (lane>>4)*4 + j
    int r16 = lane & 15, rg = lane >> 4;
    #pragma unroll
    for (int m = 0; m < 4; ++m) {
        #pragma unroll
        for (int j = 0; j < 4; ++j) {
            int rr = row0 + wr * 64 + m * 16 + rg * 4 + j;
            if (MODE == 0) {
                unsigned short* Cb = (unsigned short*)Cout;
                #pragma unroll
                for (int n = 0; n < 4; ++n) {
                    int cc = n0 + wc * 64 + n * 16 + r16;
                    float v = acc[m][n][j];
                    v = v > 0.f ? v * v : 0.f;
                    Cb[(size_t)rr * N + cc] = f2b(v);
                }
            } else if (MODE == 2) {
                if (rr < rowEnd) {
                    unsigned short* Cb = (unsigned short*)Cout;
                    float scale = pw[rr];
                    #pragma unroll
                    for (int n = 0; n < 4; ++n) {
                        int cc = n0 + wc * 64 + n * 16 + r16;
                        float v = acc[m][n][j];
                        v = v > 0.f ? v * v : 0.f;
                        Cb[(size_t)rr * N + cc] = f2b(v * scale);
                    }
                }
            } else if (MODE == 1) {
                float* Cf = (float*)Cout;
                #pragma unroll
                for (int n = 0; n < 4; ++n) {
                    int cc = n0 + wc * 64 + n * 16 + r16;
                    Cf[(size_t)rr * N + cc] = acc[m][n][j];
                }
            } else { // MODE 3
                if (rr < rowEnd) {
                    int tok = perm[rr];
                    #pragma unroll
                    for (int n = 0; n < 4; ++n) {
                        int cc = n0 + wc * 64 + n * 16 + r16;
                        atomicAdd(&outbuf[(size_t)tok * HID + cc], acc[m][n][j]);
                    }
                }
            }
        }
    }
}

extern "C" void kernel_launch(void* const* d_in, const int* in_sizes, int n_in,
                              void* d_out, int out_size, void* d_ws, size_t ws_size,
                              hipStream_t stream) {
    const float* x     = (const float*)d_in[0];
    const float* rw    = (const float*)d_in[1];
    const float* rb    = (const float*)d_in[2];
    const float* w_up  = (const float*)d_in[3];
    const float* w_dn  = (const float*)d_in[4];
    const float* sh_up = (const float*)d_in[5];
    const float* sh_dn = (const float*)d_in[6];
    float* out = (float*)d_out;
    char* ws = (char*)d_ws;

    int*   counts  = (int*)(ws);
    int*   cursors = (int*)(ws + 128);
    int*   offsets = (int*)(ws + 256);
    int*   tidx    = (int*)(ws + 1024);
    float* tw      = (float*)(ws + 1024 + 49152);
    int*   perm    = (int*)(ws + 102400);
    float* pw      = (float*)(ws + 102400 + 49152);
    unsigned short* act   = (unsigned short*)(ws + 204800);                 // [12288][1024] bf16
    unsigned short* shact = (unsigned short*)(ws + 204800 + 25165824);      // [2048][4096] bf16

    hipMemsetAsync(ws, 0, 256, stream);  // counts + cursors
    router_kernel<<<T_TOK, 256, 0, stream>>>(x, rw, rb, tidx, tw, counts);
    scan_kernel<<<1, 64, 0, stream>>>(counts, offsets);
    scatter_kernel<<<(T_TOK + 255) / 256, 256, 0, stream>>>(tidx, tw, offsets, cursors, perm, pw);

    // shared expert: up then down (down initializes out with plain stores)
    gemm_kernel<0><<<dim3(DSZ / 128, T_TOK / 128), 256, 0, stream>>>(
        x, sh_up, shact, nullptr, nullptr, nullptr, nullptr);
    gemm_kernel<1><<<dim3(HID / 128, T_TOK / 128), 256, 0, stream>>>(
        shact, sh_dn, out, nullptr, nullptr, nullptr, nullptr);

    // routed experts
    gemm_kernel<2><<<dim3(DF / 128, T_TOK / 128, NE), 256, 0, stream>>>(
        x, w_up, act, offsets, perm, pw, nullptr);
    gemm_kernel<3><<<dim3(HID / 128, T_TOK / 128, NE), 256, 0, stream>>>(
        act, w_dn, nullptr, offsets, perm, pw, out);
}

// Round 2
// 646.885 us; speedup vs baseline: 2.7455x; 2.7455x over previous
//
#include <hip/hip_runtime.h>
#include <hip/hip_bf16.h>
#include <math.h>

#define T_TOK 2048
#define HID   2048
#define NE    32
#define DF    1024
#define DSZ   4096
#define TOPK  6
#define NGRP  8
#define TOPKG 4
#define RSCALE 2.5f

typedef __attribute__((ext_vector_type(8))) short short8;
typedef __attribute__((ext_vector_type(4))) float f32x4;

static __device__ __forceinline__ unsigned short f2b(float f) {
    union { float f; unsigned u; } v; v.f = f;
    unsigned r = v.u + 0x7fffu + ((v.u >> 16) & 1u);
    return (unsigned short)(r >> 16);
}

// ---------------- router ----------------
__global__ void router_kernel(const float* __restrict__ x,
                              const float* __restrict__ rw,
                              const float* __restrict__ rb,
                              int* __restrict__ tidx, float* __restrict__ tw,
                              int* __restrict__ counts) {
    __shared__ float xs[HID];
    __shared__ float part[256];
    __shared__ float scores[NE];
    __shared__ float sfc[NE];
    int t = blockIdx.x;
    int tid = threadIdx.x;
    for (int i = tid; i < HID / 4; i += 256) {
        ((float4*)xs)[i] = ((const float4*)(x + (size_t)t * HID))[i];
    }
    __syncthreads();
    int e = tid & 31, ch = tid >> 5;
    const float* w = rw + (size_t)e * HID + ch * 256;
    const float* xv = xs + ch * 256;
    float p = 0.f;
    #pragma unroll 8
    for (int k = 0; k < 256; ++k) p += xv[k] * w[k];
    part[tid] = p;
    __syncthreads();
    if (tid < 32) {
        float l = 0.f;
        #pragma unroll
        for (int c = 0; c < 8; ++c) l += part[c * 32 + tid];
        float s = 1.f / (1.f + expf(-l));
        scores[tid] = s;
        sfc[tid] = s + rb[tid];
    }
    __syncthreads();
    if (tid == 0) {
        float gs[NGRP];
        for (int g = 0; g < NGRP; ++g) {
            float v[4];
            for (int i = 0; i < 4; ++i) v[i] = sfc[g * 4 + i];
            int bi = 0;
            for (int i = 1; i < 4; ++i) if (v[i] > v[bi]) bi = i;
            float m1 = v[bi]; v[bi] = -INFINITY;
            int bj = 0;
            for (int i = 1; i < 4; ++i) if (v[i] > v[bj]) bj = i;
            gs[g] = m1 + v[bj];
        }
        bool gsel[NGRP];
        for (int g = 0; g < NGRP; ++g) gsel[g] = false;
        for (int k = 0; k < TOPKG; ++k) {
            int bi = -1; float b = -INFINITY;
            for (int g = 0; g < NGRP; ++g)
                if (!gsel[g] && gs[g] > b) { b = gs[g]; bi = g; }
            gsel[bi] = true;
        }
        float masked[NE];
        for (int i = 0; i < NE; ++i) masked[i] = gsel[i >> 2] ? sfc[i] : 0.0f;
        int sel[TOPK]; float wv[TOPK]; float wsum = 0.f;
        for (int k = 0; k < TOPK; ++k) {
            int bi = -1; float b = -INFINITY;
            for (int i = 0; i < NE; ++i)
                if (masked[i] > b) { b = masked[i]; bi = i; }
            masked[bi] = -INFINITY;
            sel[k] = bi; wv[k] = scores[bi]; wsum += wv[k];
        }
        float inv = RSCALE / (wsum + 1e-20f);
        for (int k = 0; k < TOPK; ++k) {
            tidx[t * TOPK + k] = sel[k];
            tw[t * TOPK + k] = wv[k] * inv;
            atomicAdd(&counts[sel[k]], 1);
        }
    }
}

__global__ void scan_kernel(const int* __restrict__ counts, int* __restrict__ offsets) {
    if (threadIdx.x == 0) {
        int a = 0;
        for (int e2 = 0; e2 < NE; ++e2) { offsets[e2] = a; a += counts[e2]; }
        offsets[NE] = a;
    }
}

__global__ void scatter_kernel(const int* __restrict__ tidx, const float* __restrict__ tw,
                               const int* __restrict__ offsets, int* __restrict__ cursors,
                               int* __restrict__ perm, float* __restrict__ pw) {
    int t = blockIdx.x * blockDim.x + threadIdx.x;
    if (t >= T_TOK) return;
    for (int k = 0; k < TOPK; ++k) {
        int e = tidx[t * TOPK + k];
        int pos = atomicAdd(&cursors[e], 1);
        int slot = offsets[e] + pos;
        perm[slot] = t;
        pw[slot] = tw[t * TOPK + k];
    }
}

// ---------------- conversions ----------------
__global__ void cvt_x_kernel(const float* __restrict__ src, unsigned short* __restrict__ dst, int n8) {
    int i = blockIdx.x * blockDim.x + threadIdx.x;
    if (i >= n8) return;
    float4 a = ((const float4*)src)[i * 2];
    float4 b = ((const float4*)src)[i * 2 + 1];
    short8 o;
    o[0] = (short)f2b(a.x); o[1] = (short)f2b(a.y); o[2] = (short)f2b(a.z); o[3] = (short)f2b(a.w);
    o[4] = (short)f2b(b.x); o[5] = (short)f2b(b.y); o[6] = (short)f2b(b.z); o[7] = (short)f2b(b.w);
    *(short8*)(dst + (size_t)i * 8) = o;
}

// [K,N] fp32 -> [N,K] bf16, batched over blockIdx.z
__global__ void transpose_bf16_kernel(const float* __restrict__ src, unsigned short* __restrict__ dst,
                                      int K, int N) {
    __shared__ unsigned short tile[64][72];
    size_t mat = blockIdx.z;
    src += mat * (size_t)K * N;
    dst += mat * (size_t)K * N;
    int k0 = blockIdx.y * 64, n0 = blockIdx.x * 64;
    int tid = threadIdx.x;
    int r = tid >> 4, c4 = (tid & 15) * 4;
    #pragma unroll
    for (int p = 0; p < 4; ++p) {
        int kk = r + p * 16;
        float4 v = *(const float4*)(src + (size_t)(k0 + kk) * N + n0 + c4);
        tile[c4 + 0][kk] = f2b(v.x);
        tile[c4 + 1][kk] = f2b(v.y);
        tile[c4 + 2][kk] = f2b(v.z);
        tile[c4 + 3][kk] = f2b(v.w);
    }
    __syncthreads();
    int nr = tid >> 3, kc = (tid & 7) * 8;
    #pragma unroll
    for (int p = 0; p < 2; ++p) {
        int nn = nr + p * 32;
        short8 o;
        #pragma unroll
        for (int i = 0; i < 8; ++i) o[i] = tile[nn][kc + i];
        *(short8*)(dst + (size_t)(n0 + nn) * K + k0 + kc) = o;
    }
}

// ---------------- GEMM ----------------
// MODE 0: shared up   : A=x, B=shared_up, C=shact bf16, relu2
// MODE 1: shared down : A=shact bf16, B=shared_down, C=out fp32 store
// MODE 2: routed up   : A=x gathered(perm), B=w_up[e], C=act bf16, relu2*pw
// MODE 3: routed down : A=act bf16 (slots), B=w_down[e], C=out fp32 atomicAdd
// AB16: A is bf16 (else fp32, converted during staging)
// BT:   B is pre-transposed bf16 [N,K] (else original fp32 [K,N], strided staging)
template<int MODE, int AB16, int BT>
__global__ __launch_bounds__(256, 2)
void gemm_kernel(const void* __restrict__ Ain, const void* __restrict__ Bin,
                 void* __restrict__ Cout, const int* __restrict__ offsets,
                 const int* __restrict__ perm, const float* __restrict__ pw,
                 float* __restrict__ outbuf) {
    constexpr int K = (MODE == 0 || MODE == 2) ? HID : (MODE == 1 ? DSZ : DF);
    constexpr int N = (MODE == 0) ? DSZ : (MODE == 2 ? DF : HID);
    constexpr bool GATH = (MODE == 2);

    __shared__ __align__(16) char lds[32768];
    char* As = lds;
    char* Bs = lds + 16384;

    int tid = threadIdx.x;
    int lane = tid & 63, wvid = tid >> 6, wr = wvid >> 1, wc = wvid & 1;

    int row0, rowEnd;
    int e = 0;
    if (MODE == 2 || MODE == 3) {
        e = blockIdx.z;
        int off = offsets[e], end = offsets[e + 1];
        row0 = off + blockIdx.y * 128;
        if (row0 >= end) return;
        rowEnd = end;
    } else {
        row0 = blockIdx.y * 128;
        rowEnd = 1 << 30;
    }
    int n0 = blockIdx.x * 128;

    // staging roles: row = p*32 + (tid>>3), 16B chunk = tid&7
    int sr = tid >> 3;
    int sc = tid & 7;
    size_t asrc[4];
    #pragma unroll
    for (int p = 0; p < 4; ++p) {
        int gr = row0 + p * 32 + sr;
        if ((MODE == 2 || MODE == 3) && gr > rowEnd - 1) gr = rowEnd - 1;
        int s = GATH ? perm[gr] : gr;
        asrc[p] = (size_t)s * K;
    }
    // strided-B fallback role
    int bcol = tid & 127;
    int bkh = tid >> 7;

    f32x4 acc[4][4] = {};

    for (int k0 = 0; k0 < K; k0 += 64) {
        __syncthreads();
        // stage A: 128 rows x 64 k bf16, XOR swizzle
        #pragma unroll
        for (int p = 0; p < 4; ++p) {
            int r = p * 32 + sr;
            short8 av;
            if (AB16) {
                av = *(const short8*)((const unsigned short*)Ain + asrc[p] + k0 + sc * 8);
            } else {
                const float* src = (const float*)Ain + asrc[p] + k0 + sc * 8;
                float4 v0 = *(const float4*)(src);
                float4 v1 = *(const float4*)(src + 4);
                av[0] = (short)f2b(v0.x); av[1] = (short)f2b(v0.y);
                av[2] = (short)f2b(v0.z); av[3] = (short)f2b(v0.w);
                av[4] = (short)f2b(v1.x); av[5] = (short)f2b(v1.y);
                av[6] = (short)f2b(v1.z); av[7] = (short)f2b(v1.w);
            }
            *(short8*)(As + r * 128 + ((sc * 16) ^ ((r & 7) << 4))) = av;
        }
        // stage B
        if (BT) {
            const unsigned short* Btb = (const unsigned short*)Bin + (size_t)e * N * K;
            #pragma unroll
            for (int p = 0; p < 4; ++p) {
                int r = p * 32 + sr;
                short8 bv = *(const short8*)(Btb + (size_t)(n0 + r) * K + k0 + sc * 8);
                *(short8*)(Bs + r * 128 + ((sc * 16) ^ ((r & 7) << 4))) = bv;
            }
        } else {
            const float* B = (const float*)Bin + (size_t)e * (size_t)K * N;
            const float* bs = B + (size_t)(k0 + bkh * 32) * N + (n0 + bcol);
            short8 bv[4];
            #pragma unroll
            for (int q = 0; q < 4; ++q)
                #pragma unroll
                for (int i = 0; i < 8; ++i)
                    bv[q][i] = (short)f2b(bs[(size_t)(q * 8 + i) * N]);
            int swz = (bcol & 7) << 4;
            #pragma unroll
            for (int q = 0; q < 4; ++q)
                *(short8*)(Bs + bcol * 128 + ((bkh * 64 + q * 16) ^ swz)) = bv[q];
        }
        __syncthreads();
        // compute: 2 k-steps of 32
        #pragma unroll
        for (int ks = 0; ks < 2; ++ks) {
            int kg = lane >> 4, r16 = lane & 15;
            short8 af[4], bfr[4];
            #pragma unroll
            for (int m = 0; m < 4; ++m) {
                int r = wr * 64 + m * 16 + r16;
                af[m] = *(const short8*)(As + r * 128 + ((ks * 64 + kg * 16) ^ ((r & 7) << 4)));
            }
            #pragma unroll
            for (int n = 0; n < 4; ++n) {
                int c = wc * 64 + n * 16 + r16;
                bfr[n] = *(const short8*)(Bs + c * 128 + ((ks * 64 + kg * 16) ^ ((c & 7) << 4)));
            }
            #pragma unroll
            for (int m = 0; m < 4; ++m)
                #pragma unroll
                for (int n = 0; n < 4; ++n)
                    acc[m][n] = __builtin_amdgcn_mfma_f32_16x16x32_bf16(af[m], bfr[n], acc[m][n], 0, 0, 0);
        }
    }

    // epilogue. D frag: col = lane&15, row = (lane>>4)*4 + j
    int r16 = lane & 15, rg = lane >> 4;
    #pragma unroll
    for (int m = 0; m < 4; ++m) {
        #pragma unroll
        for (int j = 0; j < 4; ++j) {
            int rr = row0 + wr * 64 + m * 16 + rg * 4 + j;
            if (MODE == 0) {
                unsigned short* Cb = (unsigned short*)Cout;
                #pragma unroll
                for (int n = 0; n < 4; ++n) {
                    int cc = n0 + wc * 64 + n * 16 + r16;
                    float v = acc[m][n][j];
                    v = v > 0.f ? v * v : 0.f;
                    Cb[(size_t)rr * N + cc] = f2b(v);
                }
            } else if (MODE == 2) {
                if (rr < rowEnd) {
                    unsigned short* Cb = (unsigned short*)Cout;
                    float scale = pw[rr];
                    #pragma unroll
                    for (int n = 0; n < 4; ++n) {
                        int cc = n0 + wc * 64 + n * 16 + r16;
                        float v = acc[m][n][j];
                        v = v > 0.f ? v * v : 0.f;
                        Cb[(size_t)rr * N + cc] = f2b(v * scale);
                    }
                }
            } else if (MODE == 1) {
                float* Cf = (float*)Cout;
                #pragma unroll
                for (int n = 0; n < 4; ++n) {
                    int cc = n0 + wc * 64 + n * 16 + r16;
                    Cf[(size_t)rr * N + cc] = acc[m][n][j];
                }
            } else { // MODE 3
                if (rr < rowEnd) {
                    int tok = perm[rr];
                    #pragma unroll
                    for (int n = 0; n < 4; ++n) {
                        int cc = n0 + wc * 64 + n * 16 + r16;
                        unsafeAtomicAdd(&outbuf[(size_t)tok * HID + cc], acc[m][n][j]);
                    }
                }
            }
        }
    }
}

extern "C" void kernel_launch(void* const* d_in, const int* in_sizes, int n_in,
                              void* d_out, int out_size, void* d_ws, size_t ws_size,
                              hipStream_t stream) {
    const float* x     = (const float*)d_in[0];
    const float* rw    = (const float*)d_in[1];
    const float* rb    = (const float*)d_in[2];
    const float* w_up  = (const float*)d_in[3];
    const float* w_dn  = (const float*)d_in[4];
    const float* sh_up = (const float*)d_in[5];
    const float* sh_dn = (const float*)d_in[6];
    float* out = (float*)d_out;
    char* ws = (char*)d_ws;

    int*   counts  = (int*)(ws);
    int*   cursors = (int*)(ws + 128);
    int*   offsets = (int*)(ws + 256);
    int*   tidx    = (int*)(ws + 1024);
    float* tw      = (float*)(ws + 1024 + 49152);
    int*   perm    = (int*)(ws + 102400);
    float* pw      = (float*)(ws + 102400 + 49152);
    unsigned short* act   = (unsigned short*)(ws + 204800);                  // [12288][1024] bf16
    unsigned short* shact = (unsigned short*)(ws + 204800 + 25165824);       // [2048][4096] bf16
    unsigned short* xb    = (unsigned short*)(ws + 204800 + 25165824 + 16777216); // [2048][2048] bf16
    const size_t base_end = 204800ull + 25165824ull + 16777216ull + 8388608ull;   // 50536448
    unsigned short* buf   = (unsigned short*)(ws + base_end);                // reused transpose buffer

    int lvl;
    if (ws_size < base_end) lvl = 0;
    else if (ws_size >= base_end + 134217728ull) lvl = 3;   // full: routed weights transposed
    else if (ws_size >= base_end + 16777216ull) lvl = 2;    // shared weights transposed only
    else lvl = 1;                                           // bf16 x only

    hipMemsetAsync(ws, 0, 256, stream);  // counts + cursors
    router_kernel<<<T_TOK, 256, 0, stream>>>(x, rw, rb, tidx, tw, counts);
    scan_kernel<<<1, 64, 0, stream>>>(counts, offsets);
    scatter_kernel<<<(T_TOK + 255) / 256, 256, 0, stream>>>(tidx, tw, offsets, cursors, perm, pw);
    if (lvl >= 1) cvt_x_kernel<<<T_TOK * HID / 8 / 256, 256, 0, stream>>>(x, xb, T_TOK * HID / 8);

    dim3 gridS0(DSZ / 128, T_TOK / 128);
    dim3 gridS1(HID / 128, T_TOK / 128);
    dim3 gridR2(DF / 128, T_TOK / 128, NE);
    dim3 gridR3(HID / 128, T_TOK / 128, NE);

    // shared up
    if (lvl >= 2) {
        transpose_bf16_kernel<<<dim3(DSZ / 64, HID / 64, 1), 256, 0, stream>>>(sh_up, buf, HID, DSZ);
        gemm_kernel<0, 1, 1><<<gridS0, 256, 0, stream>>>(xb, buf, shact, nullptr, nullptr, nullptr, nullptr);
    } else if (lvl == 1) {
        gemm_kernel<0, 1, 0><<<gridS0, 256, 0, stream>>>(xb, sh_up, shact, nullptr, nullptr, nullptr, nullptr);
    } else {
        gemm_kernel<0, 0, 0><<<gridS0, 256, 0, stream>>>(x, sh_up, shact, nullptr, nullptr, nullptr, nullptr);
    }
    // shared down (initializes out with plain stores)
    if (lvl >= 2) {
        transpose_bf16_kernel<<<dim3(HID / 64, DSZ / 64, 1), 256, 0, stream>>>(sh_dn, buf, DSZ, HID);
        gemm_kernel<1, 1, 1><<<gridS1, 256, 0, stream>>>(shact, buf, out, nullptr, nullptr, nullptr, nullptr);
    } else {
        gemm_kernel<1, 1, 0><<<gridS1, 256, 0, stream>>>(shact, sh_dn, out, nullptr, nullptr, nullptr, nullptr);
    }
    // routed up
    if (lvl >= 3) {
        transpose_bf16_kernel<<<dim3(DF / 64, HID / 64, NE), 256, 0, stream>>>(w_up, buf, HID, DF);
        gemm_kernel<2, 1, 1><<<gridR2, 256, 0, stream>>>(xb, buf, act, offsets, perm, pw, nullptr);
    } else if (lvl >= 1) {
        gemm_kernel<2, 1, 0><<<gridR2, 256, 0, stream>>>(xb, w_up, act, offsets, perm, pw, nullptr);
    } else {
        gemm_kernel<2, 0, 0><<<gridR2, 256, 0, stream>>>(x, w_up, act, offsets, perm, pw, nullptr);
    }
    // routed down (atomicAdd into out)
    if (lvl >= 3) {
        transpose_bf16_kernel<<<dim3(HID / 64, DF / 64, NE), 256, 0, stream>>>(w_dn, buf, DF, HID);
        gemm_kernel<3, 1, 1><<<gridR3, 256, 0, stream>>>(act, buf, nullptr, offsets, perm, pw, out);
    } else {
        gemm_kernel<3, 1, 0><<<gridR3, 256, 0, stream>>>(act, w_dn, nullptr, offsets, perm, pw, out);
    }
}

// Round 3
// 627.953 us; speedup vs baseline: 2.8282x; 1.0301x over previous
//
#include <hip/hip_runtime.h>
#include <hip/hip_bf16.h>
#include <math.h>

#define T_TOK 2048
#define HID   2048
#define NE    32
#define DF    1024
#define DSZ   4096
#define TOPK  6
#define NGRP  8
#define TOPKG 4
#define RSCALE 2.5f

typedef __attribute__((ext_vector_type(8))) short short8;
typedef __attribute__((ext_vector_type(4))) float f32x4;

typedef __attribute__((address_space(1))) const void gv1;
typedef __attribute__((address_space(3))) void lv3;

static __device__ __forceinline__ void gload16(const void* g, void* l) {
    __builtin_amdgcn_global_load_lds((gv1*)g, (lv3*)l, 16, 0, 0);
}

static __device__ __forceinline__ unsigned short f2b(float f) {
    union { float f; unsigned u; } v; v.f = f;
    unsigned r = v.u + 0x7fffu + ((v.u >> 16) & 1u);
    return (unsigned short)(r >> 16);
}

// ---------------- router (fused x->bf16) ----------------
__global__ void router_kernel(const float* __restrict__ x,
                              const float* __restrict__ rw,
                              const float* __restrict__ rb,
                              int* __restrict__ tidx, float* __restrict__ tw,
                              int* __restrict__ counts,
                              unsigned short* __restrict__ xb) {
    __shared__ float xs[HID];
    __shared__ float part[256];
    __shared__ float scores[NE];
    __shared__ float sfc[NE];
    int t = blockIdx.x;
    int tid = threadIdx.x;
    for (int i = tid; i < HID / 4; i += 256) {
        ((float4*)xs)[i] = ((const float4*)(x + (size_t)t * HID))[i];
    }
    __syncthreads();
    // fused bf16 conversion of this token's row
    if (xb) {
        float4 a = ((const float4*)xs)[tid * 2];
        float4 b = ((const float4*)xs)[tid * 2 + 1];
        short8 o;
        o[0] = (short)f2b(a.x); o[1] = (short)f2b(a.y); o[2] = (short)f2b(a.z); o[3] = (short)f2b(a.w);
        o[4] = (short)f2b(b.x); o[5] = (short)f2b(b.y); o[6] = (short)f2b(b.z); o[7] = (short)f2b(b.w);
        *(short8*)(xb + (size_t)t * HID + tid * 8) = o;
    }
    int e = tid & 31, ch = tid >> 5;
    const float* w = rw + (size_t)e * HID + ch * 256;
    const float* xv = xs + ch * 256;
    float p = 0.f;
    #pragma unroll 8
    for (int k = 0; k < 256; ++k) p += xv[k] * w[k];
    part[tid] = p;
    __syncthreads();
    if (tid < 32) {
        float l = 0.f;
        #pragma unroll
        for (int c = 0; c < 8; ++c) l += part[c * 32 + tid];
        float s = 1.f / (1.f + expf(-l));
        scores[tid] = s;
        sfc[tid] = s + rb[tid];
    }
    __syncthreads();
    if (tid == 0) {
        float gs[NGRP];
        for (int g = 0; g < NGRP; ++g) {
            float v[4];
            for (int i = 0; i < 4; ++i) v[i] = sfc[g * 4 + i];
            int bi = 0;
            for (int i = 1; i < 4; ++i) if (v[i] > v[bi]) bi = i;
            float m1 = v[bi]; v[bi] = -INFINITY;
            int bj = 0;
            for (int i = 1; i < 4; ++i) if (v[i] > v[bj]) bj = i;
            gs[g] = m1 + v[bj];
        }
        bool gsel[NGRP];
        for (int g = 0; g < NGRP; ++g) gsel[g] = false;
        for (int k = 0; k < TOPKG; ++k) {
            int bi = -1; float b = -INFINITY;
            for (int g = 0; g < NGRP; ++g)
                if (!gsel[g] && gs[g] > b) { b = gs[g]; bi = g; }
            gsel[bi] = true;
        }
        float masked[NE];
        for (int i = 0; i < NE; ++i) masked[i] = gsel[i >> 2] ? sfc[i] : 0.0f;
        int sel[TOPK]; float wv[TOPK]; float wsum = 0.f;
        for (int k = 0; k < TOPK; ++k) {
            int bi = -1; float b = -INFINITY;
            for (int i = 0; i < NE; ++i)
                if (masked[i] > b) { b = masked[i]; bi = i; }
            masked[bi] = -INFINITY;
            sel[k] = bi; wv[k] = scores[bi]; wsum += wv[k];
        }
        float inv = RSCALE / (wsum + 1e-20f);
        for (int k = 0; k < TOPK; ++k) {
            tidx[t * TOPK + k] = sel[k];
            tw[t * TOPK + k] = wv[k] * inv;
            atomicAdd(&counts[sel[k]], 1);
        }
    }
}

__global__ void scan_kernel(const int* __restrict__ counts, int* __restrict__ offsets) {
    if (threadIdx.x == 0) {
        int a = 0;
        for (int e2 = 0; e2 < NE; ++e2) { offsets[e2] = a; a += counts[e2]; }
        offsets[NE] = a;
    }
}

__global__ void scatter_kernel(const int* __restrict__ tidx, const float* __restrict__ tw,
                               const int* __restrict__ offsets, int* __restrict__ cursors,
                               int* __restrict__ perm, float* __restrict__ pw,
                               int* __restrict__ slot_of) {
    int t = blockIdx.x * blockDim.x + threadIdx.x;
    if (t >= T_TOK) return;
    for (int k = 0; k < TOPK; ++k) {
        int e = tidx[t * TOPK + k];
        int pos = atomicAdd(&cursors[e], 1);
        int slot = offsets[e] + pos;
        perm[slot] = t;
        pw[slot] = tw[t * TOPK + k];
        slot_of[t * TOPK + k] = slot;
    }
}

// ---------------- conversions ----------------
__global__ void cvt_x_kernel(const float* __restrict__ src, unsigned short* __restrict__ dst, int n8) {
    int i = blockIdx.x * blockDim.x + threadIdx.x;
    if (i >= n8) return;
    float4 a = ((const float4*)src)[i * 2];
    float4 b = ((const float4*)src)[i * 2 + 1];
    short8 o;
    o[0] = (short)f2b(a.x); o[1] = (short)f2b(a.y); o[2] = (short)f2b(a.z); o[3] = (short)f2b(a.w);
    o[4] = (short)f2b(b.x); o[5] = (short)f2b(b.y); o[6] = (short)f2b(b.z); o[7] = (short)f2b(b.w);
    *(short8*)(dst + (size_t)i * 8) = o;
}

// [K,N] fp32 -> [N,K] bf16, batched over blockIdx.z
__global__ void transpose_bf16_kernel(const float* __restrict__ src, unsigned short* __restrict__ dst,
                                      int K, int N) {
    __shared__ unsigned short tile[64][72];
    size_t mat = blockIdx.z;
    src += mat * (size_t)K * N;
    dst += mat * (size_t)K * N;
    int k0 = blockIdx.y * 64, n0 = blockIdx.x * 64;
    int tid = threadIdx.x;
    int r = tid >> 4, c4 = (tid & 15) * 4;
    #pragma unroll
    for (int p = 0; p < 4; ++p) {
        int kk = r + p * 16;
        float4 v = *(const float4*)(src + (size_t)(k0 + kk) * N + n0 + c4);
        tile[c4 + 0][kk] = f2b(v.x);
        tile[c4 + 1][kk] = f2b(v.y);
        tile[c4 + 2][kk] = f2b(v.z);
        tile[c4 + 3][kk] = f2b(v.w);
    }
    __syncthreads();
    int nr = tid >> 3, kc = (tid & 7) * 8;
    #pragma unroll
    for (int p = 0; p < 2; ++p) {
        int nn = nr + p * 32;
        short8 o;
        #pragma unroll
        for (int i = 0; i < 8; ++i) o[i] = tile[nn][kc + i];
        *(short8*)(dst + (size_t)(n0 + nn) * K + k0 + kc) = o;
    }
}

// ---------------- combine: out[t] += sum_k slotout[slot(t,k)] ----------------
__global__ void combine_kernel(const float* __restrict__ slotout, const int* __restrict__ slot_of,
                               float* __restrict__ out) {
    int t = blockIdx.x, tid = threadIdx.x;
    int s[TOPK];
    #pragma unroll
    for (int k = 0; k < TOPK; ++k) s[k] = slot_of[t * TOPK + k];
    #pragma unroll
    for (int p = 0; p < 2; ++p) {
        int c = (p * 256 + tid) * 4;
        float4 a = *(const float4*)(out + (size_t)t * HID + c);
        #pragma unroll
        for (int k = 0; k < TOPK; ++k) {
            float4 v = *(const float4*)(slotout + (size_t)s[k] * HID + c);
            a.x += v.x; a.y += v.y; a.z += v.z; a.w += v.w;
        }
        *(float4*)(out + (size_t)t * HID + c) = a;
    }
}

// ---------------- GEMM ----------------
// MODE 0: shared up   : A=x, B=shared_up, C=shact bf16, relu2
// MODE 1: shared down : A=shact bf16, B=shared_down, C=out fp32 store
// MODE 2: routed up   : A=x gathered(perm), B=w_up[e], C=act bf16, relu2*pw
// MODE 3: routed down : A=act bf16 (slots), B=w_down[e], C: SLOT? slotout store : atomicAdd out
// AB16: A is bf16; BT: B pre-transposed bf16 [N,K]; GL: global_load_lds staging (needs AB16&&BT)
template<int MODE, int AB16, int BT, int GL, int SLOT>
__global__ __launch_bounds__(256, 2)
void gemm_kernel(const void* __restrict__ Ain, const void* __restrict__ Bin,
                 void* __restrict__ Cout, const int* __restrict__ offsets,
                 const int* __restrict__ perm, const float* __restrict__ pw,
                 float* __restrict__ outbuf) {
    constexpr int K = (MODE == 0 || MODE == 2) ? HID : (MODE == 1 ? DSZ : DF);
    constexpr int N = (MODE == 0) ? DSZ : (MODE == 2 ? DF : HID);
    constexpr bool GATH = (MODE == 2);

    __shared__ __align__(16) char lds[32768];
    char* As = lds;
    char* Bs = lds + 16384;

    int tid = threadIdx.x;
    int lane = tid & 63, wvid = tid >> 6, wr = wvid >> 1, wc = wvid & 1;

    int row0, rowEnd;
    int e = 0;
    if (MODE == 2 || MODE == 3) {
        e = blockIdx.z;
        int off = offsets[e], end = offsets[e + 1];
        row0 = off + blockIdx.y * 128;
        if (row0 >= end) return;
        rowEnd = end;
    } else {
        row0 = blockIdx.y * 128;
        rowEnd = 1 << 30;
    }
    int n0 = blockIdx.x * 128;

    // ---- staging role precompute ----
    // GL path: wave issue p covers rows p*32 + wvid*8 .. +8, linear LDS dest,
    // source chunk permuted so LDS layout == XOR-swizzled ((r&7) == lane>>3).
    int lr = lane >> 3;
    int csrc = (((lane & 7) ^ lr) << 4);
    size_t abyte[4], bbyte[4];
    int ldsoff[4];
    // non-GL path roles
    int sr = tid >> 3, sc = tid & 7;
    size_t asrc[4];
    if (GL) {
        #pragma unroll
        for (int p = 0; p < 4; ++p) {
            int r = p * 32 + wvid * 8 + lr;
            int gr = row0 + r;
            if ((MODE == 2 || MODE == 3) && gr > rowEnd - 1) gr = rowEnd - 1;
            int s = GATH ? perm[gr] : gr;
            abyte[p] = (size_t)s * (K * 2);
            bbyte[p] = (size_t)(n0 + r) * (K * 2);
            ldsoff[p] = (p * 32 + wvid * 8) * 128;
        }
    } else {
        #pragma unroll
        for (int p = 0; p < 4; ++p) {
            int gr = row0 + p * 32 + sr;
            if ((MODE == 2 || MODE == 3) && gr > rowEnd - 1) gr = rowEnd - 1;
            int s = GATH ? perm[gr] : gr;
            asrc[p] = (size_t)s * K;
        }
    }
    int bcol = tid & 127;
    int bkh = tid >> 7;

    const char* Ab = (const char*)Ain;
    const char* Bb = (const char*)Bin + (size_t)e * ((size_t)N * K * 2);

    f32x4 acc[4][4] = {};

    for (int k0 = 0; k0 < K; k0 += 64) {
        __syncthreads();
        if (GL) {
            #pragma unroll
            for (int p = 0; p < 4; ++p) {
                gload16(Ab + abyte[p] + k0 * 2 + csrc, As + ldsoff[p]);
                gload16(Bb + bbyte[p] + k0 * 2 + csrc, Bs + ldsoff[p]);
            }
        } else {
            // stage A
            #pragma unroll
            for (int p = 0; p < 4; ++p) {
                int r = p * 32 + sr;
                short8 av;
                if (AB16) {
                    av = *(const short8*)((const unsigned short*)Ain + asrc[p] + k0 + sc * 8);
                } else {
                    const float* src = (const float*)Ain + asrc[p] + k0 + sc * 8;
                    float4 v0 = *(const float4*)(src);
                    float4 v1 = *(const float4*)(src + 4);
                    av[0] = (short)f2b(v0.x); av[1] = (short)f2b(v0.y);
                    av[2] = (short)f2b(v0.z); av[3] = (short)f2b(v0.w);
                    av[4] = (short)f2b(v1.x); av[5] = (short)f2b(v1.y);
                    av[6] = (short)f2b(v1.z); av[7] = (short)f2b(v1.w);
                }
                *(short8*)(As + r * 128 + ((sc * 16) ^ ((r & 7) << 4))) = av;
            }
            // stage B
            if (BT) {
                const unsigned short* Btb = (const unsigned short*)Bin + (size_t)e * N * K;
                #pragma unroll
                for (int p = 0; p < 4; ++p) {
                    int r = p * 32 + sr;
                    short8 bv = *(const short8*)(Btb + (size_t)(n0 + r) * K + k0 + sc * 8);
                    *(short8*)(Bs + r * 128 + ((sc * 16) ^ ((r & 7) << 4))) = bv;
                }
            } else {
                const float* B = (const float*)Bin + (size_t)e * (size_t)K * N;
                const float* bs = B + (size_t)(k0 + bkh * 32) * N + (n0 + bcol);
                short8 bv[4];
                #pragma unroll
                for (int q = 0; q < 4; ++q)
                    #pragma unroll
                    for (int i = 0; i < 8; ++i)
                        bv[q][i] = (short)f2b(bs[(size_t)(q * 8 + i) * N]);
                int swz = (bcol & 7) << 4;
                #pragma unroll
                for (int q = 0; q < 4; ++q)
                    *(short8*)(Bs + bcol * 128 + ((bkh * 64 + q * 16) ^ swz)) = bv[q];
            }
        }
        __syncthreads();
        // compute: 2 k-steps of 32
        #pragma unroll
        for (int ks = 0; ks < 2; ++ks) {
            int kg = lane >> 4, r16 = lane & 15;
            short8 af[4], bfr[4];
            #pragma unroll
            for (int m = 0; m < 4; ++m) {
                int r = wr * 64 + m * 16 + r16;
                af[m] = *(const short8*)(As + r * 128 + ((ks * 64 + kg * 16) ^ ((r & 7) << 4)));
            }
            #pragma unroll
            for (int n = 0; n < 4; ++n) {
                int c = wc * 64 + n * 16 + r16;
                bfr[n] = *(const short8*)(Bs + c * 128 + ((ks * 64 + kg * 16) ^ ((c & 7) << 4)));
            }
            #pragma unroll
            for (int m = 0; m < 4; ++m)
                #pragma unroll
                for (int n = 0; n < 4; ++n)
                    acc[m][n] = __builtin_amdgcn_mfma_f32_16x16x32_bf16(af[m], bfr[n], acc[m][n], 0, 0, 0);
        }
    }

    // epilogue. D frag: col = lane&15, row = (lane>>4)*4 + j
    int r16 = lane & 15, rg = lane >> 4;
    #pragma unroll
    for (int m = 0; m < 4; ++m) {
        #pragma unroll
        for (int j = 0; j < 4; ++j) {
            int rr = row0 + wr * 64 + m * 16 + rg * 4 + j;
            if (MODE == 0) {
                unsigned short* Cb = (unsigned short*)Cout;
                #pragma unroll
                for (int n = 0; n < 4; ++n) {
                    int cc = n0 + wc * 64 + n * 16 + r16;
                    float v = acc[m][n][j];
                    v = v > 0.f ? v * v : 0.f;
                    Cb[(size_t)rr * N + cc] = f2b(v);
                }
            } else if (MODE == 2) {
                if (rr < rowEnd) {
                    unsigned short* Cb = (unsigned short*)Cout;
                    float scale = pw[rr];
                    #pragma unroll
                    for (int n = 0; n < 4; ++n) {
                        int cc = n0 + wc * 64 + n * 16 + r16;
                        float v = acc[m][n][j];
                        v = v > 0.f ? v * v : 0.f;
                        Cb[(size_t)rr * N + cc] = f2b(v * scale);
                    }
                }
            } else if (MODE == 1) {
                float* Cf = (float*)Cout;
                #pragma unroll
                for (int n = 0; n < 4; ++n) {
                    int cc = n0 + wc * 64 + n * 16 + r16;
                    Cf[(size_t)rr * N + cc] = acc[m][n][j];
                }
            } else { // MODE 3
                if (rr < rowEnd) {
                    if (SLOT) {
                        float* Cf = (float*)Cout;
                        #pragma unroll
                        for (int n = 0; n < 4; ++n) {
                            int cc = n0 + wc * 64 + n * 16 + r16;
                            Cf[(size_t)rr * N + cc] = acc[m][n][j];
                        }
                    } else {
                        int tok = perm[rr];
                        #pragma unroll
                        for (int n = 0; n < 4; ++n) {
                            int cc = n0 + wc * 64 + n * 16 + r16;
                            unsafeAtomicAdd(&outbuf[(size_t)tok * HID + cc], acc[m][n][j]);
                        }
                    }
                }
            }
        }
    }
}

extern "C" void kernel_launch(void* const* d_in, const int* in_sizes, int n_in,
                              void* d_out, int out_size, void* d_ws, size_t ws_size,
                              hipStream_t stream) {
    const float* x     = (const float*)d_in[0];
    const float* rw    = (const float*)d_in[1];
    const float* rb    = (const float*)d_in[2];
    const float* w_up  = (const float*)d_in[3];
    const float* w_dn  = (const float*)d_in[4];
    const float* sh_up = (const float*)d_in[5];
    const float* sh_dn = (const float*)d_in[6];
    float* out = (float*)d_out;
    char* ws = (char*)d_ws;

    int*   counts  = (int*)(ws);
    int*   cursors = (int*)(ws + 128);
    int*   offsets = (int*)(ws + 256);
    int*   tidx    = (int*)(ws + 1024);
    float* tw      = (float*)(ws + 50176);
    int*   perm    = (int*)(ws + 102400);
    float* pw      = (float*)(ws + 151552);
    int*   slot_of = (int*)(ws + 200704);
    unsigned short* act   = (unsigned short*)(ws + 249856);      // [12288][1024] bf16
    unsigned short* shact = (unsigned short*)(ws + 25415680);    // [2048][4096] bf16
    unsigned short* xb    = (unsigned short*)(ws + 42192896);    // [2048][2048] bf16
    const size_t base_end = 50581504ull;
    unsigned short* buf   = (unsigned short*)(ws + base_end);    // reused transpose buffer (<=128MB)
    const size_t buf_end  = base_end + 134217728ull;             // 184799232
    float* slotout = (float*)(ws + buf_end);                     // [12288][2048] fp32 (100MB)
    const size_t slot_end = buf_end + 100663296ull;              // 285462528

    int lvl;
    if (ws_size < base_end) lvl = 0;
    else if (ws_size >= buf_end) lvl = 3;
    else if (ws_size >= base_end + 33554432ull) lvl = 2;
    else lvl = 1;
    bool use_slot = (lvl >= 3) && (ws_size >= slot_end);

    hipMemsetAsync(ws, 0, 256, stream);  // counts + cursors
    router_kernel<<<T_TOK, 256, 0, stream>>>(x, rw, rb, tidx, tw, counts, lvl >= 1 ? xb : nullptr);
    scan_kernel<<<1, 64, 0, stream>>>(counts, offsets);
    scatter_kernel<<<(T_TOK + 255) / 256, 256, 0, stream>>>(tidx, tw, offsets, cursors, perm, pw, slot_of);

    dim3 gridS0(DSZ / 128, T_TOK / 128);
    dim3 gridS1(HID / 128, T_TOK / 128);
    dim3 gridR2(DF / 128, T_TOK / 128, NE);
    dim3 gridR3(HID / 128, T_TOK / 128, NE);

    // shared up
    if (lvl >= 2) {
        transpose_bf16_kernel<<<dim3(DSZ / 64, HID / 64, 1), 256, 0, stream>>>(sh_up, buf, HID, DSZ);
        gemm_kernel<0, 1, 1, 1, 0><<<gridS0, 256, 0, stream>>>(xb, buf, shact, nullptr, nullptr, nullptr, nullptr);
    } else if (lvl == 1) {
        gemm_kernel<0, 1, 0, 0, 0><<<gridS0, 256, 0, stream>>>(xb, sh_up, shact, nullptr, nullptr, nullptr, nullptr);
    } else {
        gemm_kernel<0, 0, 0, 0, 0><<<gridS0, 256, 0, stream>>>(x, sh_up, shact, nullptr, nullptr, nullptr, nullptr);
    }
    // shared down (initializes out with plain stores)
    if (lvl >= 2) {
        transpose_bf16_kernel<<<dim3(HID / 64, DSZ / 64, 1), 256, 0, stream>>>(sh_dn, buf, DSZ, HID);
        gemm_kernel<1, 1, 1, 1, 0><<<gridS1, 256, 0, stream>>>(shact, buf, out, nullptr, nullptr, nullptr, nullptr);
    } else {
        gemm_kernel<1, 1, 0, 0, 0><<<gridS1, 256, 0, stream>>>(shact, sh_dn, out, nullptr, nullptr, nullptr, nullptr);
    }
    // routed up
    if (lvl >= 3) {
        transpose_bf16_kernel<<<dim3(DF / 64, HID / 64, NE), 256, 0, stream>>>(w_up, buf, HID, DF);
        gemm_kernel<2, 1, 1, 1, 0><<<gridR2, 256, 0, stream>>>(xb, buf, act, offsets, perm, pw, nullptr);
    } else if (lvl >= 1) {
        gemm_kernel<2, 1, 0, 0, 0><<<gridR2, 256, 0, stream>>>(xb, w_up, act, offsets, perm, pw, nullptr);
    } else {
        gemm_kernel<2, 0, 0, 0, 0><<<gridR2, 256, 0, stream>>>(x, w_up, act, offsets, perm, pw, nullptr);
    }
    // routed down
    if (lvl >= 3) {
        transpose_bf16_kernel<<<dim3(HID / 64, DF / 64, NE), 256, 0, stream>>>(w_dn, buf, DF, HID);
        if (use_slot) {
            gemm_kernel<3, 1, 1, 1, 1><<<gridR3, 256, 0, stream>>>(act, buf, slotout, offsets, perm, pw, nullptr);
            combine_kernel<<<T_TOK, 256, 0, stream>>>(slotout, slot_of, out);
        } else {
            gemm_kernel<3, 1, 1, 1, 0><<<gridR3, 256, 0, stream>>>(act, buf, nullptr, offsets, perm, pw, out);
        }
    } else {
        gemm_kernel<3, 1, 0, 0, 0><<<gridR3, 256, 0, stream>>>(act, w_dn, nullptr, offsets, perm, pw, out);
    }
}